// Round 22
// baseline (392.966 us; speedup 1.0000x reference)
//
#include <hip/hip_runtime.h>
#include <hip/hip_bf16.h>
#include <math.h>

using bf16 = __hip_bfloat16;

static constexpr int B = 2, C = 192, Hh = 128, Ww = 128, N = Hh * Ww;
static constexpr int M = 128, RD = 10, GS = 256, NG = N / GS;
static constexpr int HEADS = 4, HD = C / HEADS;                      // 48
static constexpr int TDF = 16, HID = 4 * C, HIDT = HID + TDF;        // 768, 784
static constexpr int TC3 = 3 * C;                                    // 576
static constexpr int NCAT = TC3 + HID;                               // 1344
static constexpr float LOG_M = 4.852030263919617f;                   // ln(128)
static constexpr float ATT_SCALE = 0.14433756729740643f;             // 48^-0.5

typedef __attribute__((ext_vector_type(8))) short bf16x8;
typedef __attribute__((ext_vector_type(4))) float f32x4;

__device__ __forceinline__ float b2f(bf16 v) { return __bfloat162float(v); }
__device__ __forceinline__ bf16 f2b(float v) { return __float2bfloat16(v); }
__device__ __forceinline__ float bits2f(unsigned short u) { return __uint_as_float(((unsigned)u) << 16); }
__device__ __forceinline__ unsigned short f2bits(float f) {
    union { bf16 h; unsigned short u; } cv; cv.h = f2b(f); return cv.u;
}
// fast gelu via A&S 7.1.26 erf approx (max abs err 1.5e-7) + HW exp
__device__ __forceinline__ float gelu_fast(float v) {
    float x = v * 0.70710678118654752f;
    float ax = fabsf(x);
    float t = 1.0f / (1.0f + 0.3275911f * ax);
    float y = t * (0.254829592f + t * (-0.284496736f + t * (1.421413741f +
              t * (-1.453152027f + t * 1.061405429f))));
    float e = __expf(-ax * ax);
    float erfv = 1.0f - y * e;
    erfv = copysignf(erfv, x);
    return 0.5f * v * (1.0f + erfv);
}

// ---------- weight transpose+convert: in[K][Nn] f32 -> out[Nn][K] bf16 ----------
__global__ void __launch_bounds__(256) k_wtrans(const float* in, bf16* out, int K, int Nn) {
    __shared__ float T[64][65];
    int n0 = blockIdx.x * 64, k0 = blockIdx.y * 64;
    int tid = threadIdx.x;
    for (int e = tid; e < 4096; e += 256) {
        int kk = e >> 6, nn = e & 63;
        if (k0 + kk < K) T[kk][nn] = in[(size_t)(k0 + kk) * Nn + n0 + nn];
    }
    __syncthreads();
    for (int e = tid; e < 4096; e += 256) {
        int nn = e >> 6, kk = e & 63;
        if (k0 + kk < K) out[(size_t)(n0 + nn) * K + k0 + kk] = f2b(T[kk][nn]);
    }
}

// ---------- combined gain-folded weight prep: WcatT[n][k] = g[k]*W[k][n] ----------
__global__ void __launch_bounds__(256) k_wprep(const float* wqkv_w, const float* fc1_w,
                                               const float* g1, const float* g2, bf16* WcatT) {
    __shared__ float T[192 * 65];
    __shared__ float gl[192];
    int n0 = blockIdx.x * 64;
    int tid = threadIdx.x;
    bool isq = (n0 < TC3);
    const float* W = isq ? wqkv_w : fc1_w;
    const float* g = isq ? g1 : g2;
    int Nn = isq ? TC3 : HID;
    int nb = isq ? n0 : n0 - TC3;
    for (int k = tid; k < 192; k += 256) gl[k] = g[k];
    __syncthreads();
    for (int e = tid; e < 192 * 64; e += 256) {
        int k = e >> 6, nn = e & 63;
        T[k * 65 + nn] = W[(size_t)k * Nn + nb + nn] * gl[k];
    }
    __syncthreads();
    for (int e = tid; e < 64 * 192; e += 256) {
        int nn = e / 192, k = e % 192;
        WcatT[(size_t)(n0 + nn) * C + k] = f2b(T[k * 65 + nn]);
    }
}

// ---------- folded bias: bcat[n] = bias[n] + sum_k beta[k]*W[k][n] ----------
__global__ void k_bprep(const float* wqkv_w, const float* fc1_w, const float* wqkv_b,
                        const float* fc1_b, const float* b1, const float* b2v, float* bcat) {
    int n = blockIdx.x * 256 + threadIdx.x;
    if (n >= NCAT) return;
    float s;
    if (n < TC3) {
        s = wqkv_b[n];
        for (int k = 0; k < C; ++k) s += b1[k] * wqkv_w[(size_t)k * TC3 + n];
    } else {
        int nn = n - TC3;
        s = fc1_b[nn];
        for (int k = 0; k < C; ++k) s += b2v[k] * fc1_w[(size_t)k * HID + nn];
    }
    bcat[n] = s;
}

// ---------- K0: token-dict precompute: kn, vvT (bf16), td_feat ----------
__global__ void k_precompute(const float* td, const float* wk_w, const float* wk_b,
                             const float* wv_w, const float* wv_b,
                             const float* fc_td_w, const float* fc_td_b,
                             float* kn, bf16* vvT, float* tdf) {
    int m = blockIdx.x;
    int lane = threadIdx.x;      // 64
    __shared__ float trow[C];
    for (int ch = lane; ch < C; ch += 64) trow[ch] = td[m * C + ch];
    __syncthreads();
    __shared__ float ks[RD];
    __shared__ float inv_s;
    if (lane < RD) {
        float s = wk_b[lane];
        for (int ch = 0; ch < C; ++ch) s += trow[ch] * wk_w[ch * RD + lane];
        ks[lane] = s;
    }
    __syncthreads();
    if (lane == 0) {
        float ss = 0.f;
        for (int r = 0; r < RD; ++r) ss += ks[r] * ks[r];
        inv_s = 1.0f / fmaxf(sqrtf(ss), 1e-12f);
    }
    __syncthreads();
    if (lane < RD) kn[m * RD + lane] = ks[lane] * inv_s;
    for (int c0 = 0; c0 < 3; ++c0) {
        int co = lane + 64 * c0;
        float s = wv_b[co];
        for (int ch = 0; ch < C; ++ch) s += trow[ch] * wv_w[ch * C + co];
        vvT[(size_t)co * M + m] = f2b(s);
    }
    if (lane < TDF) {
        float s = fc_td_b[lane];
        for (int ch = 0; ch < C; ++ch) s += trow[ch] * fc_td_w[ch * TDF + lane];
        tdf[m * TDF + lane] = s;
    }
}

// ---------- K1: LN core via LDS transpose: xn (bf16, no gains), xn32, acc(fp32)=x ----------
__global__ void __launch_bounds__(256) k_ln(const float* x, bf16* xn, float* xn32, float* acc) {
    __shared__ float Xs[64 * 193];
    __shared__ float mu_s[64], rs_s[64];
    int tid = threadIdx.x;
    int m0 = blockIdx.x * 64;
    int b = m0 / N, i0 = m0 % N;
    for (int e = tid; e < 192 * 64; e += 256) {
        int ch = e >> 6, ii = e & 63;
        Xs[ii * 193 + ch] = x[((size_t)b * C + ch) * N + i0 + ii];
    }
    __syncthreads();
    {
        int tok = tid >> 2, part = tid & 3;
        float s = 0.f, ss = 0.f;
        for (int ch = part * 48; ch < part * 48 + 48; ++ch) {
            float v = Xs[tok * 193 + ch]; s += v; ss += v * v;
        }
        s += __shfl_xor(s, 1); ss += __shfl_xor(ss, 1);
        s += __shfl_xor(s, 2); ss += __shfl_xor(ss, 2);
        if (part == 0) {
            float mu = s / C;
            mu_s[tok] = mu;
            rs_s[tok] = rsqrtf(ss / C - mu * mu + 1e-5f);
        }
    }
    __syncthreads();
    for (int e = tid; e < 64 * 192; e += 256) {
        int ii = e / 192, ch = e % 192;
        float v = Xs[ii * 193 + ch];
        float xnv = (v - mu_s[ii]) * rs_s[ii];
        size_t g = (size_t)(m0 + ii);
        xn[g * C + ch] = f2b(xnv);
        xn32[g * C + ch] = xnv;
        acc[g * C + ch] = v;
    }
}

// ---------- K2: ATD_CA front-end ----------
__global__ void __launch_bounds__(256) k_atdca(const float* xn32, const float* g1, const float* b1,
                        const float* wq_w, const float* wq_b, const float* ca_scale,
                        const float* kn, bf16* p_buf, int* tk_id) {
    int t0 = blockIdx.x * 4;
    int w = threadIdx.x >> 6, lane = threadIdx.x & 63;
    int g = t0 + w;
    float xn[3];
    #pragma unroll
    for (int k = 0; k < 3; ++k) {
        int ch = lane + 64 * k;
        xn[k] = xn32[(size_t)g * C + ch] * g1[ch] + b1[ch];
    }
    float q[RD];
    #pragma unroll
    for (int r = 0; r < RD; ++r) {
        float p = 0.f;
        #pragma unroll
        for (int k = 0; k < 3; ++k) { int ch = lane + 64 * k; p += xn[k] * wq_w[ch * RD + r]; }
        for (int mk = 32; mk >= 1; mk >>= 1) p += __shfl_xor(p, mk);
        q[r] = p + wq_b[r];
    }
    float ssn = 0.f;
    #pragma unroll
    for (int r = 0; r < RD; ++r) ssn += q[r] * q[r];
    float invq = 1.0f / fmaxf(sqrtf(ssn), 1e-12f);
    float s0 = 0.f, s1 = 0.f;
    #pragma unroll
    for (int r = 0; r < RD; ++r) {
        float qr = q[r] * invq;
        s0 += qr * kn[lane * RD + r];
        s1 += qr * kn[(lane + 64) * RD + r];
    }
    float mv; int mi;
    if (s1 > s0) { mv = s1; mi = lane + 64; } else { mv = s0; mi = lane; }
    for (int mk = 32; mk >= 1; mk >>= 1) {
        float ov = __shfl_xor(mv, mk); int oi = __shfl_xor(mi, mk);
        if (ov > mv || (ov == mv && oi < mi)) { mv = ov; mi = oi; }
    }
    float cs = ca_scale[0]; cs = fminf(fmaxf(cs, 0.0f), 3.0f);
    float scale = 1.0f + cs * LOG_M;
    float e0 = expf((s0 - mv) * scale), e1 = expf((s1 - mv) * scale);
    float sum = e0 + e1;
    for (int mk = 32; mk >= 1; mk >>= 1) sum += __shfl_xor(sum, mk);
    float invs = 1.0f / sum;
    p_buf[(size_t)g * M + lane] = f2b(e0 * invs);
    p_buf[(size_t)g * M + lane + 64] = f2b(e1 * invs);
    if (lane == 0) tk_id[g] = mi;
}

// ---------- K2b: acc += p_buf @ vvT  (MFMA GEMM, K=128, fp32 RMW) ----------
__global__ void __launch_bounds__(256) k_pv(const bf16* p_buf, const bf16* vvT, float* acc) {
    __shared__ __align__(16) short As[64 * 136];
    __shared__ __align__(16) short Bs[64 * 136];
    int tid = threadIdx.x;
    int m0 = blockIdx.x * 64;
    int n0 = blockIdx.y * 64;
    for (int e = tid; e < 64 * 16; e += 256) {
        int m = e >> 4, kc = (e & 15) * 8;
        *(uint4*)&As[m * 136 + kc] = *(const uint4*)(p_buf + (size_t)(m0 + m) * M + kc);
    }
    for (int e = tid; e < 64 * 16; e += 256) {
        int n = e >> 4, kc = (e & 15) * 8;
        *(uint4*)&Bs[n * 136 + kc] = *(const uint4*)(vvT + (size_t)(n0 + n) * M + kc);
    }
    __syncthreads();
    int w = tid >> 6, lane = tid & 63;
    int wm = (w >> 1) * 32, wn = (w & 1) * 32;
    int lr = lane & 15, lk = (lane >> 4) * 8;
    f32x4 acc00 = {0.f,0.f,0.f,0.f}, acc01 = acc00, acc10 = acc00, acc11 = acc00;
    #pragma unroll
    for (int ks = 0; ks < 4; ++ks) {
        int k0 = ks * 32 + lk;
        bf16x8 a0 = *(bf16x8*)&As[(wm + lr) * 136 + k0];
        bf16x8 a1 = *(bf16x8*)&As[(wm + 16 + lr) * 136 + k0];
        bf16x8 b0 = *(bf16x8*)&Bs[(wn + lr) * 136 + k0];
        bf16x8 b1 = *(bf16x8*)&Bs[(wn + 16 + lr) * 136 + k0];
        acc00 = __builtin_amdgcn_mfma_f32_16x16x32_bf16(a0, b0, acc00, 0, 0, 0);
        acc01 = __builtin_amdgcn_mfma_f32_16x16x32_bf16(a0, b1, acc01, 0, 0, 0);
        acc10 = __builtin_amdgcn_mfma_f32_16x16x32_bf16(a1, b0, acc10, 0, 0, 0);
        acc11 = __builtin_amdgcn_mfma_f32_16x16x32_bf16(a1, b1, acc11, 0, 0, 0);
    }
    int rbase = (lane >> 4) * 4;
    f32x4 accs[2][2] = {{acc00, acc01}, {acc10, acc11}};
    #pragma unroll
    for (int mt = 0; mt < 2; ++mt) {
        #pragma unroll
        for (int nt = 0; nt < 2; ++nt) {
            int co = n0 + wn + nt * 16 + lr;
            #pragma unroll
            for (int r = 0; r < 4; ++r) {
                int tok = m0 + wm + mt * 16 + rbase + r;
                acc[(size_t)tok * C + co] += accs[mt][nt][r];
            }
        }
    }
}

// ---------- fused qkv+fc1 GEMM v4: 64x96 tile, SWAPPED-operand MFMA ->
// ---------- lane holds 4 consecutive output channels -> packed uint2 stores, no epilogue LDS ----------
__global__ void __launch_bounds__(256) k_gemm_fused(const bf16* Abuf, const bf16* Wt, const float* bias,
                                                    bf16* qkv, bf16* hcat) {
    __shared__ __align__(16) unsigned short As[64 * 104];
    __shared__ __align__(16) unsigned short Bs[96 * 104];
    int tid = threadIdx.x;
    int m0 = blockIdx.x * 64, n0 = blockIdx.y * 96;
    int w = tid >> 6, lane = tid & 63;
    int wm = (w >> 1) * 32, wn = (w & 1) * 48;
    int lr = lane & 15, g8 = lane >> 4;
    f32x4 acc[2][3];
    #pragma unroll
    for (int mt = 0; mt < 2; ++mt)
        #pragma unroll
        for (int nt = 0; nt < 3; ++nt) acc[mt][nt] = (f32x4){0.f,0.f,0.f,0.f};
    for (int kc = 0; kc < 2; ++kc) {
        int kb = kc * 96;
        __syncthreads();
        for (int e = tid; e < 64 * 12; e += 256) {
            int m = e / 12, blk = e % 12;
            *(uint4*)&As[m * 104 + blk * 8] = *(const uint4*)(Abuf + (size_t)(m0 + m) * C + kb + blk * 8);
        }
        for (int e = tid; e < 96 * 12; e += 256) {
            int n = e / 12, blk = e % 12;
            *(uint4*)&Bs[n * 104 + blk * 8] = *(const uint4*)(Wt + (size_t)(n0 + n) * C + kb + blk * 8);
        }
        __syncthreads();
        #pragma unroll
        for (int ks = 0; ks < 3; ++ks) {
            int blk = ks * 4 + g8;
            bf16x8 a[2];
            bf16x8 bfr[3];
            #pragma unroll
            for (int mt = 0; mt < 2; ++mt) a[mt] = *(bf16x8*)&As[(wm + mt * 16 + lr) * 104 + blk * 8];
            #pragma unroll
            for (int nt = 0; nt < 3; ++nt) bfr[nt] = *(bf16x8*)&Bs[(wn + nt * 16 + lr) * 104 + blk * 8];
            // SWAPPED: first operand = weights -> output "row" = channel, "col" = token
            #pragma unroll
            for (int mt = 0; mt < 2; ++mt)
                #pragma unroll
                for (int nt = 0; nt < 3; ++nt)
                    acc[mt][nt] = __builtin_amdgcn_mfma_f32_16x16x32_bf16(bfr[nt], a[mt], acc[mt][nt], 0, 0, 0);
        }
    }
    bool isq = (n0 < TC3);
    // epilogue: lane owns token (m0+wm+mt*16+lr), channels (n0+wn+nt*16+g8*4 .. +3)
    #pragma unroll
    for (int mt = 0; mt < 2; ++mt) {
        int tok = m0 + wm + mt * 16 + lr;
        #pragma unroll
        for (int nt = 0; nt < 3; ++nt) {
            int ch = n0 + wn + nt * 16 + g8 * 4;
            float4 bv = *(const float4*)(bias + ch);
            const float* bp = (const float*)&bv;
            unsigned short pk[4];
            #pragma unroll
            for (int r = 0; r < 4; ++r) {
                float v = acc[mt][nt][r] + bp[r];
                pk[r] = f2bits(isq ? v : gelu_fast(v));
            }
            if (isq) *(uint2*)(qkv + (size_t)tok * TC3 + ch) = *(uint2*)pk;
            else     *(uint2*)(hcat + (size_t)tok * HIDT + (ch - TC3)) = *(uint2*)pk;
        }
    }
}

// ---------- K3: MFMA GEMM, tile 128x96, K=192 (proj), swapped-operand packed epilogue ----------
template<int OUTLD, int MODE>
__global__ void __launch_bounds__(256) k_gemm_big(const bf16* Abuf, const bf16* Wt, const float* bias,
                                                  bf16* outb, float* outf) {
    __shared__ __align__(16) unsigned short As[128 * 104];
    __shared__ __align__(16) unsigned short Bs[96 * 104];
    int tid = threadIdx.x;
    int m0 = blockIdx.x * 128, n0 = blockIdx.y * 96;
    int w = tid >> 6, lane = tid & 63;
    int wm = (w >> 1) * 64, wn = (w & 1) * 48;
    int lr = lane & 15, g8 = lane >> 4;
    f32x4 acc[4][3];
    #pragma unroll
    for (int mt = 0; mt < 4; ++mt)
        #pragma unroll
        for (int nt = 0; nt < 3; ++nt) acc[mt][nt] = (f32x4){0.f,0.f,0.f,0.f};
    for (int kc = 0; kc < 2; ++kc) {
        int kb = kc * 96;
        __syncthreads();
        for (int e = tid; e < 128 * 12; e += 256) {
            int m = e / 12, blk = e % 12;
            *(uint4*)&As[m * 104 + blk * 8] = *(const uint4*)(Abuf + (size_t)(m0 + m) * C + kb + blk * 8);
        }
        for (int e = tid; e < 96 * 12; e += 256) {
            int n = e / 12, blk = e % 12;
            *(uint4*)&Bs[n * 104 + blk * 8] = *(const uint4*)(Wt + (size_t)(n0 + n) * C + kb + blk * 8);
        }
        __syncthreads();
        #pragma unroll
        for (int ks = 0; ks < 3; ++ks) {
            int blk = ks * 4 + g8;
            bf16x8 a[4];
            bf16x8 bfr[3];
            #pragma unroll
            for (int mt = 0; mt < 4; ++mt) a[mt] = *(bf16x8*)&As[(wm + mt * 16 + lr) * 104 + blk * 8];
            #pragma unroll
            for (int nt = 0; nt < 3; ++nt) bfr[nt] = *(bf16x8*)&Bs[(wn + nt * 16 + lr) * 104 + blk * 8];
            #pragma unroll
            for (int mt = 0; mt < 4; ++mt)
                #pragma unroll
                for (int nt = 0; nt < 3; ++nt)
                    acc[mt][nt] = __builtin_amdgcn_mfma_f32_16x16x32_bf16(bfr[nt], a[mt], acc[mt][nt], 0, 0, 0);
        }
    }
    #pragma unroll
    for (int mt = 0; mt < 4; ++mt) {
        int tok = m0 + wm + mt * 16 + lr;
        #pragma unroll
        for (int nt = 0; nt < 3; ++nt) {
            int ch = n0 + wn + nt * 16 + g8 * 4;
            float4 bv = *(const float4*)(bias + ch);
            const float* bp = (const float*)&bv;
            unsigned short pk[4];
            #pragma unroll
            for (int r = 0; r < 4; ++r) {
                float v = acc[mt][nt][r] + bp[r];
                pk[r] = f2bits(MODE == 1 ? gelu_fast(v) : v);
            }
            *(uint2*)(outb + (size_t)tok * OUTLD + ch) = *(uint2*)pk;
        }
    }
}

// ---------- Stable counting sort by tk_id ----------
__global__ void k_sort_count(const int* tk_id, int* chunk_cnt) {
    int c = blockIdx.x, b = blockIdx.y;
    int tid = threadIdx.x;               // 128
    __shared__ int cnt[M];
    cnt[tid] = 0;
    __syncthreads();
    atomicAdd(&cnt[tk_id[b * N + c * 128 + tid]], 1);
    __syncthreads();
    chunk_cnt[(b * 128 + c) * M + tid] = cnt[tid];
}

__global__ void k_sort_scan(int* chunk_cnt) {
    int b = blockIdx.x;
    int k = threadIdx.x;
    int tot = 0;
    for (int c = 0; c < 128; ++c) tot += chunk_cnt[(b * 128 + c) * M + k];
    __shared__ int totals[M];
    __shared__ int base[M];
    totals[k] = tot;
    __syncthreads();
    if (k == 0) {
        int run = 0;
        for (int kk = 0; kk < M; ++kk) { base[kk] = run; run += totals[kk]; }
    }
    __syncthreads();
    int run = base[k];
    for (int c = 0; c < 128; ++c) {
        int v = chunk_cnt[(b * 128 + c) * M + k];
        chunk_cnt[(b * 128 + c) * M + k] = run;
        run += v;
    }
}

__global__ void k_sort_scatter(const int* tk_id, const int* chunk_cnt, int* sort_idx) {
    int c = blockIdx.x, b = blockIdx.y;
    int k = threadIdx.x;
    __shared__ int keys[128];
    keys[k] = tk_id[b * N + c * 128 + k];
    __syncthreads();
    int off = chunk_cnt[(b * 128 + c) * M + k];
    for (int j = 0; j < 128; ++j) {
        if (keys[j] == k) sort_idx[b * N + off++] = c * 128 + j;
    }
}

// ---------- MFMA grouped self-attention: block = (group, head, batch) ----------
__global__ void __launch_bounds__(256) k_attn_mfma(const bf16* qkv, const int* sort_idx, bf16* o_buf) {
    int g = blockIdx.x, h = blockIdx.y, b = blockIdx.z;
    __shared__ int sidx[GS];
    __shared__ __align__(16) unsigned short Kl[256 * 64];
    __shared__ __align__(16) unsigned short Vt[48 * 256];
    __shared__ __align__(16) unsigned short Pl[4][64 * 32];
    int tid = threadIdx.x;
    sidx[tid] = sort_idx[b * N + g * GS + tid];
    __syncthreads();
    {
        int row = tid;
        int srow = sidx[row];
        size_t kb = ((size_t)(b * N + srow)) * TC3 + C + h * HD;
        size_t vb = ((size_t)(b * N + srow)) * TC3 + 2 * C + h * HD;
        #pragma unroll
        for (int db = 0; db < 6; ++db) {
            uint4 kv = *(const uint4*)(qkv + kb + db * 8);
            *(uint4*)&Kl[row * 64 + ((db ^ (row & 7)) * 8)] = kv;
            uint4 vv4 = *(const uint4*)(qkv + vb + db * 8);
            unsigned short* vu = (unsigned short*)&vv4;
            #pragma unroll
            for (int j = 0; j < 8; ++j) {
                int d = db * 8 + j;
                Vt[d * 256 + (((row >> 3) ^ (d & 7)) * 8) + (row & 7)] = vu[j];
            }
        }
        uint4 z = {0u,0u,0u,0u};
        *(uint4*)&Kl[row * 64 + ((6 ^ (row & 7)) * 8)] = z;
        *(uint4*)&Kl[row * 64 + ((7 ^ (row & 7)) * 8)] = z;
    }
    __syncthreads();
    int w = tid >> 6, l = tid & 63;
    int lq = l & 15, g8 = l >> 4;
    bf16x8 qf[4][2];
    #pragma unroll
    for (int qt = 0; qt < 4; ++qt) {
        int qrow = sidx[w * 64 + qt * 16 + lq];
        size_t qb = ((size_t)(b * N + qrow)) * TC3 + h * HD;
        qf[qt][0] = *(const bf16x8*)(qkv + qb + g8 * 8);
        int d1 = 32 + g8 * 8;
        if (d1 < HD) qf[qt][1] = *(const bf16x8*)(qkv + qb + d1);
        else { uint4 z = {0u,0u,0u,0u}; qf[qt][1] = *(bf16x8*)&z; }
    }
    float mrun[4], lrun[4];
    f32x4 Oa[4][3];
    #pragma unroll
    for (int qt = 0; qt < 4; ++qt) {
        mrun[qt] = -1e30f; lrun[qt] = 0.f;
        #pragma unroll
        for (int dt = 0; dt < 3; ++dt) Oa[qt][dt] = (f32x4){0.f,0.f,0.f,0.f};
    }
    unsigned short* Pw = &Pl[w][0];
    for (int ck = 0; ck < 8; ++ck) {
        int kbase = ck * 32;
        bf16x8 kf[2][2];
        #pragma unroll
        for (int kt = 0; kt < 2; ++kt) {
            int key = kbase + kt * 16 + lq;
            #pragma unroll
            for (int ks = 0; ks < 2; ++ks)
                kf[kt][ks] = *(bf16x8*)&Kl[key * 64 + (((ks * 4 + g8) ^ (key & 7)) * 8)];
        }
        bf16x8 vf[3];
        #pragma unroll
        for (int dt = 0; dt < 3; ++dt) {
            int d = dt * 16 + lq;
            vf[dt] = *(bf16x8*)&Vt[d * 256 + ((((kbase >> 3) + g8) ^ (d & 7)) * 8)];
        }
        #pragma unroll
        for (int qt = 0; qt < 4; ++qt) {
            f32x4 s0 = {0.f,0.f,0.f,0.f}, s1 = s0;
            s0 = __builtin_amdgcn_mfma_f32_16x16x32_bf16(kf[0][0], qf[qt][0], s0, 0, 0, 0);
            s0 = __builtin_amdgcn_mfma_f32_16x16x32_bf16(kf[0][1], qf[qt][1], s0, 0, 0, 0);
            s1 = __builtin_amdgcn_mfma_f32_16x16x32_bf16(kf[1][0], qf[qt][0], s1, 0, 0, 0);
            s1 = __builtin_amdgcn_mfma_f32_16x16x32_bf16(kf[1][1], qf[qt][1], s1, 0, 0, 0);
            float sv0[4], sv1[4];
            float cmax = -1e30f;
            #pragma unroll
            for (int r = 0; r < 4; ++r) {
                sv0[r] = s0[r] * ATT_SCALE; sv1[r] = s1[r] * ATT_SCALE;
                cmax = fmaxf(cmax, fmaxf(sv0[r], sv1[r]));
            }
            cmax = fmaxf(cmax, __shfl_xor(cmax, 16));
            cmax = fmaxf(cmax, __shfl_xor(cmax, 32));
            float mnew = fmaxf(mrun[qt], cmax);
            float sf = expf(mrun[qt] - mnew);
            float p0[4], p1[4], csum = 0.f;
            #pragma unroll
            for (int r = 0; r < 4; ++r) {
                p0[r] = expf(sv0[r] - mnew); p1[r] = expf(sv1[r] - mnew);
                csum += p0[r] + p1[r];
            }
            csum += __shfl_xor(csum, 16);
            csum += __shfl_xor(csum, 32);
            lrun[qt] = lrun[qt] * sf + csum;
            mrun[qt] = mnew;
            int q = qt * 16 + lq;
            {
                unsigned short pw[4];
                #pragma unroll
                for (int r = 0; r < 4; ++r) pw[r] = f2bits(p0[r]);
                int slot = g8;
                int addr = q * 32 + (((slot >> 1) ^ (q & 3)) * 8) + (slot & 1) * 4;
                *(uint2*)&Pw[addr] = *(uint2*)pw;
                #pragma unroll
                for (int r = 0; r < 4; ++r) pw[r] = f2bits(p1[r]);
                slot = 4 + g8;
                addr = q * 32 + (((slot >> 1) ^ (q & 3)) * 8) + (slot & 1) * 4;
                *(uint2*)&Pw[addr] = *(uint2*)pw;
            }
            float sfr[4];
            #pragma unroll
            for (int r = 0; r < 4; ++r) sfr[r] = __shfl(sf, 4 * g8 + r);
            #pragma unroll
            for (int dt = 0; dt < 3; ++dt)
                #pragma unroll
                for (int r = 0; r < 4; ++r) Oa[qt][dt][r] *= sfr[r];
            bf16x8 pa = *(bf16x8*)&Pw[q * 32 + ((g8 ^ (lq & 3)) * 8)];
            #pragma unroll
            for (int dt = 0; dt < 3; ++dt)
                Oa[qt][dt] = __builtin_amdgcn_mfma_f32_16x16x32_bf16(pa, vf[dt], Oa[qt][dt], 0, 0, 0);
        }
    }
    #pragma unroll
    for (int qt = 0; qt < 4; ++qt) {
        float invq = 1.0f / lrun[qt];
        float invr[4];
        #pragma unroll
        for (int r = 0; r < 4; ++r) invr[r] = __shfl(invq, 4 * g8 + r);
        #pragma unroll
        for (int r = 0; r < 4; ++r) {
            int grow = sidx[w * 64 + qt * 16 + 4 * g8 + r];
            size_t obase = ((size_t)(b * N + grow)) * C + h * HD;
            #pragma unroll
            for (int dt = 0; dt < 3; ++dt)
                o_buf[obase + dt * 16 + lq] = f2b(Oa[qt][dt][r] * invr[r]);
        }
    }
}

// ---------- td feature gather into hcat tail columns ----------
__global__ void k_tdfill(const int* tk_id, const float* tdf, bf16* hcat) {
    int idx = blockIdx.x * 256 + threadIdx.x;
    if (idx >= B * N * TDF) return;
    int tok = idx >> 4, f = idx & 15;
    hcat[(size_t)tok * HIDT + HID + f] = f2b(tdf[tk_id[tok] * TDF + f]);
}

// ---------- depthwise 5x5 conv v5b: fp32 LDS tile, unroll-1 ky loop, fast gelu ----------
__global__ void __launch_bounds__(256) k_conv(const bf16* hcat, const float* dw_w, const float* dw_b,
                                              bf16* convsum) {
    int st = blockIdx.x;
    int c16 = blockIdx.y;
    int b = blockIdx.z;
    int tx0 = (st & 7) * 16, ty0 = (st >> 3) * 16;
    int tid = threadIdx.x;
    __shared__ __align__(16) float Hf[20 * 81 * 4];
    __shared__ __align__(16) float Wf[25 * 16];
    __shared__ float Wb[16];
    for (int e = tid; e < 400; e += 256) {
        int tap = e >> 4, ch = e & 15;
        Wf[e] = dw_w[(size_t)(c16 * 16 + ch) * 25 + tap];
    }
    if (tid < 16) Wb[tid] = dw_b[c16 * 16 + tid];
    for (int e = tid; e < 800; e += 256) {
        int pos = e >> 1, sc = e & 1;
        int py = pos / 20, px = pos % 20;
        int gy = ty0 + py - 2, gx = tx0 + px - 2;
        uint4 v = {0u, 0u, 0u, 0u};
        if (gy >= 0 && gy < Hh && gx >= 0 && gx < Ww)
            v = *(const uint4*)(hcat + ((size_t)b * N + gy * Ww + gx) * HIDT + c16 * 16 + sc * 8);
        unsigned short* u = (unsigned short*)&v;
        float4 f0 = { bits2f(u[0]), bits2f(u[1]), bits2f(u[2]), bits2f(u[3]) };
        float4 f1 = { bits2f(u[4]), bits2f(u[5]), bits2f(u[6]), bits2f(u[7]) };
        int base = (py * 81 + px * 4 + sc * 2) * 4;
        *(float4*)&Hf[base] = f0;
        *(float4*)&Hf[base + 4] = f1;
    }
    __syncthreads();
    int cc = tid & 1, lx = (tid >> 1) & 7, ly = tid >> 4;
    float acc[2][8] = {};
    #pragma unroll 1
    for (int ky = 0; ky < 5; ++ky) {
        int py = ly + ky;
        float4 w[5][2];
        #pragma unroll
        for (int kx = 0; kx < 5; ++kx) {
            w[kx][0] = *(float4*)&Wf[(ky * 5 + kx) * 16 + cc * 8];
            w[kx][1] = *(float4*)&Wf[(ky * 5 + kx) * 16 + cc * 8 + 4];
        }
        #pragma unroll
        for (int c = 0; c < 6; ++c) {
            int px = 2 * lx + c;
            int base = (py * 81 + px * 4 + cc * 2) * 4;
            float4 f0 = *(float4*)&Hf[base];
            float4 f1 = *(float4*)&Hf[base + 4];
            float f[8] = { f0.x, f0.y, f0.z, f0.w, f1.x, f1.y, f1.z, f1.w };
            #pragma unroll
            for (int kx = 0; kx < 5; ++kx) {
                int ox = c - kx;
                if (ox >= 0 && ox < 2) {
                    const float* wp = (const float*)&w[kx][0];
                    #pragma unroll
                    for (int j = 0; j < 8; ++j) acc[ox][j] += f[j] * wp[j];
                }
            }
        }
    }
    int gy = ty0 + ly;
    #pragma unroll
    for (int ox = 0; ox < 2; ++ox) {
        int px = 2 * lx + ox + 2, py = ly + 2;
        int base = (py * 81 + px * 4 + cc * 2) * 4;
        float4 f0 = *(float4*)&Hf[base];
        float4 f1 = *(float4*)&Hf[base + 4];
        float cf[8] = { f0.x, f0.y, f0.z, f0.w, f1.x, f1.y, f1.z, f1.w };
        unsigned short ow[8];
        #pragma unroll
        for (int j = 0; j < 8; ++j)
            ow[j] = f2bits(cf[j] + gelu_fast(acc[ox][j] + Wb[cc * 8 + j]));
        int gx = tx0 + 2 * lx + ox;
        *(uint4*)(convsum + ((size_t)b * N + gy * Ww + gx) * HIDT + c16 * 16 + cc * 8) = *(uint4*)ow;
    }
}

// ---------- fc2 (K=784) MFMA v4: direct register GEMM; accres fp32 + aca bf16 ----------
__global__ void __launch_bounds__(256) k_fc2ln(const bf16* convsum, const bf16* Wt,
                                               const float* bias, const float* g3, const float* b3,
                                               const float* accres, const bf16* aca, float* out) {
    __shared__ float Ot[192 * 36];
    __shared__ float partS[4][32], partQ[4][32];
    int tid = threadIdx.x;
    int m0 = blockIdx.x * 32;
    int w = tid >> 6, lane = tid & 63;
    int lr = lane & 15, g8 = lane >> 4;
    int n0 = w * 48;
    f32x4 acc[2][3];
    #pragma unroll
    for (int mt = 0; mt < 2; ++mt)
        #pragma unroll
        for (int nt = 0; nt < 3; ++nt) acc[mt][nt] = (f32x4){0.f,0.f,0.f,0.f};
    const bf16* a0p = convsum + (size_t)(m0 + lr) * HIDT + g8 * 8;
    const bf16* a1p = convsum + (size_t)(m0 + 16 + lr) * HIDT + g8 * 8;
    const bf16* b0p = Wt + (size_t)(n0 + lr) * HIDT + g8 * 8;
    const bf16* b1p = Wt + (size_t)(n0 + 16 + lr) * HIDT + g8 * 8;
    const bf16* b2p = Wt + (size_t)(n0 + 32 + lr) * HIDT + g8 * 8;
    #pragma unroll 4
    for (int kk = 0; kk < 24; ++kk) {
        int k0 = kk * 32;
        bf16x8 a0 = *(const bf16x8*)(a0p + k0);
        bf16x8 a1 = *(const bf16x8*)(a1p + k0);
        bf16x8 w0 = *(const bf16x8*)(b0p + k0);
        bf16x8 w1 = *(const bf16x8*)(b1p + k0);
        bf16x8 w2 = *(const bf16x8*)(b2p + k0);
        acc[0][0] = __builtin_amdgcn_mfma_f32_16x16x32_bf16(a0, w0, acc[0][0], 0, 0, 0);
        acc[0][1] = __builtin_amdgcn_mfma_f32_16x16x32_bf16(a0, w1, acc[0][1], 0, 0, 0);
        acc[0][2] = __builtin_amdgcn_mfma_f32_16x16x32_bf16(a0, w2, acc[0][2], 0, 0, 0);
        acc[1][0] = __builtin_amdgcn_mfma_f32_16x16x32_bf16(a1, w0, acc[1][0], 0, 0, 0);
        acc[1][1] = __builtin_amdgcn_mfma_f32_16x16x32_bf16(a1, w1, acc[1][1], 0, 0, 0);
        acc[1][2] = __builtin_amdgcn_mfma_f32_16x16x32_bf16(a1, w2, acc[1][2], 0, 0, 0);
    }
    {
        uint4 z = {0u,0u,0u,0u};
        bf16x8 a0 = *(bf16x8*)&z, a1 = a0, w0 = a0, w1 = a0, w2 = a0;
        if (g8 < 2) {
            a0 = *(const bf16x8*)(a0p + 768);
            a1 = *(const bf16x8*)(a1p + 768);
            w0 = *(const bf16x8*)(b0p + 768);
            w1 = *(const bf16x8*)(b1p + 768);
            w2 = *(const bf16x8*)(b2p + 768);
        }
        acc[0][0] = __builtin_amdgcn_mfma_f32_16x16x32_bf16(a0, w0, acc[0][0], 0, 0, 0);
        acc[0][1] = __builtin_amdgcn_mfma_f32_16x16x32_bf16(a0, w1, acc[0][1], 0, 0, 0);
        acc[0][2] = __builtin_amdgcn_mfma_f32_16x16x32_bf16(a0, w2, acc[0][2], 0, 0, 0);
        acc[1][0] = __builtin_amdgcn_mfma_f32_16x16x32_bf16(a1, w0, acc[1][0], 0, 0, 0);
        acc[1][1] = __builtin_amdgcn_mfma_f32_16x16x32_bf16(a1, w1, acc[1][1], 0, 0, 0);
        acc[1][2] = __builtin_amdgcn_mfma_f32_16x16x32_bf16(a1, w2, acc[1][2], 0, 0, 0);
    }
    #pragma unroll
    for (int nt = 0; nt < 3; ++nt) {
        float bv = bias[n0 + nt * 16 + lr];
        #pragma unroll
        for (int mt = 0; mt < 2; ++mt)
            #pragma unroll
            for (int r = 0; r < 4; ++r) acc[mt][nt][r] += bv;
    }
    #pragma unroll
    for (int mt = 0; mt < 2; ++mt) {
        #pragma unroll
        for (int r = 0; r < 4; ++r) {
            float s = 0.f, q = 0.f;
            #pragma unroll
            for (int nt = 0; nt < 3; ++nt) { float v = acc[mt][nt][r]; s += v; q += v * v; }
            s += __shfl_xor(s, 1); q += __shfl_xor(q, 1);
            s += __shfl_xor(s, 2); q += __shfl_xor(q, 2);
            s += __shfl_xor(s, 4); q += __shfl_xor(q, 4);
            s += __shfl_xor(s, 8); q += __shfl_xor(q, 8);
            if (lr == 0) {
                int row = mt * 16 + g8 * 4 + r;
                partS[w][row] = s;
                partQ[w][row] = q;
            }
        }
    }
    __syncthreads();
    int bb = m0 / N, i0 = m0 % N;
    #pragma unroll
    for (int mt = 0; mt < 2; ++mt) {
        #pragma unroll
        for (int r = 0; r < 4; ++r) {
            int row = mt * 16 + g8 * 4 + r;
            float s = partS[0][row] + partS[1][row] + partS[2][row] + partS[3][row];
            float q = partQ[0][row] + partQ[1][row] + partQ[2][row] + partQ[3][row];
            float mu = s / C;
            float rstd = rsqrtf(q / C - mu * mu + 1e-5f);
            int tok = m0 + row;
            #pragma unroll
            for (int nt = 0; nt < 3; ++nt) {
                int c = n0 + nt * 16 + lr;
                float o = accres[(size_t)tok * C + c] + b2f(aca[(size_t)tok * C + c])
                        + (acc[mt][nt][r] - mu) * rstd * g3[c] + b3[c];
                Ot[c * 36 + row] = o;
            }
        }
    }
    __syncthreads();
    for (int e = tid; e < 192 * 8; e += 256) {
        int row = e >> 3, q4 = e & 7;
        float4 v = *(float4*)&Ot[row * 36 + q4 * 4];
        *(float4*)(out + ((size_t)(bb * C + row)) * N + i0 + q4 * 4) = v;
    }
}

__global__ void k_sentinel(float* out, int nelem) {
    int i = blockIdx.x * blockDim.x + threadIdx.x;
    if (i < nelem) out[i] = 1234.0f;
}

extern "C" void kernel_launch(void* const* d_in, const int* in_sizes, int n_in,
                              void* d_out, int out_size, void* d_ws, size_t ws_size,
                              hipStream_t stream) {
    const float* x        = (const float*)d_in[0];
    const float* td       = (const float*)d_in[2];
    const float* g1       = (const float*)d_in[3];
    const float* b1       = (const float*)d_in[4];
    const float* g2       = (const float*)d_in[5];
    const float* b2v      = (const float*)d_in[6];
    const float* g3       = (const float*)d_in[7];
    const float* b3       = (const float*)d_in[8];
    const float* wq_w     = (const float*)d_in[9];
    const float* wq_b     = (const float*)d_in[10];
    const float* wk_w     = (const float*)d_in[11];
    const float* wk_b     = (const float*)d_in[12];
    const float* wv_w     = (const float*)d_in[13];
    const float* wv_b     = (const float*)d_in[14];
    const float* ca_scale = (const float*)d_in[15];
    const float* wqkv_w   = (const float*)d_in[16];
    const float* wqkv_b   = (const float*)d_in[17];
    const float* proj_w   = (const float*)d_in[18];
    const float* proj_b   = (const float*)d_in[19];
    const float* fc_td_w  = (const float*)d_in[20];
    const float* fc_td_b  = (const float*)d_in[21];
    const float* fc1_w    = (const float*)d_in[22];
    const float* fc1_b    = (const float*)d_in[23];
    const float* dw_w     = (const float*)d_in[24];
    const float* dw_b     = (const float*)d_in[25];
    const float* fc2_w    = (const float*)d_in[26];
    const float* fc2_b    = (const float*)d_in[27];
    float* out = (float*)d_out;

    char* ws = (char*)d_ws;
    size_t off = 0;
    auto alloc = [&](size_t bytes) { size_t o = off; off += (bytes + 255) & ~(size_t)255; return o; };
    size_t o_xn    = alloc((size_t)B * N * C * 2);
    size_t o_xn32  = alloc((size_t)B * N * C * 4);
    size_t o_acc   = alloc((size_t)B * N * C * 4);
    size_t o_aca   = alloc((size_t)B * N * C * 2);
    size_t o_qkv   = alloc((size_t)B * N * TC3 * 2);
    size_t o_hcat  = alloc((size_t)B * N * HIDT * 2);
    size_t o_conv  = alloc((size_t)B * N * HIDT * 2);
    size_t o_obuf  = alloc((size_t)B * N * C * 2);
    size_t o_kn    = alloc((size_t)M * RD * 4);
    size_t o_vvT   = alloc((size_t)C * M * 2);
    size_t o_tdf   = alloc((size_t)M * TDF * 4);
    size_t o_tk    = alloc((size_t)B * N * 4);
    size_t o_sidx  = alloc((size_t)B * N * 4);
    size_t o_ccnt  = alloc((size_t)B * 128 * M * 4);
    size_t o_pbuf  = alloc((size_t)B * N * M * 2);
    size_t o_wcat  = alloc((size_t)NCAT * C * 2);
    size_t o_bcat  = alloc((size_t)NCAT * 4);
    size_t o_projT = alloc((size_t)C * C * 2);
    size_t o_fc2T  = alloc((size_t)C * HIDT * 2);

    if (ws_size < off) {
        k_sentinel<<<(out_size + 255) / 256, 256, 0, stream>>>(out, out_size);
        return;
    }

    bf16*  xn      = (bf16*)(ws + o_xn);
    float* xn32    = (float*)(ws + o_xn32);
    float* acc     = (float*)(ws + o_acc);
    bf16*  aca     = (bf16*)(ws + o_aca);
    bf16*  qkv     = (bf16*)(ws + o_qkv);
    bf16*  hcat    = (bf16*)(ws + o_hcat);
    bf16*  convsum = (bf16*)(ws + o_conv);
    bf16*  o_bufp  = (bf16*)(ws + o_obuf);
    float* kn      = (float*)(ws + o_kn);
    bf16*  vvT     = (bf16*)(ws + o_vvT);
    float* tdf     = (float*)(ws + o_tdf);
    int*   tk_id   = (int*)(ws + o_tk);
    int*   sidx    = (int*)(ws + o_sidx);
    int*   ccnt    = (int*)(ws + o_ccnt);
    bf16*  p_buf   = (bf16*)(ws + o_pbuf);
    bf16*  WcatT   = (bf16*)(ws + o_wcat);
    float* bcat    = (float*)(ws + o_bcat);
    bf16*  projT   = (bf16*)(ws + o_projT);
    bf16*  fc2T    = (bf16*)(ws + o_fc2T);

    k_wprep<<<NCAT / 64, 256, 0, stream>>>(wqkv_w, fc1_w, g1, g2, WcatT);
    k_bprep<<<(NCAT + 255) / 256, 256, 0, stream>>>(wqkv_w, fc1_w, wqkv_b, fc1_b, b1, b2v, bcat);
    k_wtrans<<<dim3(C / 64, C / 64), 256, 0, stream>>>(proj_w, projT, C, C);
    k_wtrans<<<dim3(C / 64, (HIDT + 63) / 64), 256, 0, stream>>>(fc2_w, fc2T, HIDT, C);

    k_precompute<<<M, 64, 0, stream>>>(td, wk_w, wk_b, wv_w, wv_b, fc_td_w, fc_td_b, kn, vvT, tdf);
    k_ln<<<B * N / 64, 256, 0, stream>>>(x, xn, xn32, acc);
    k_atdca<<<B * N / 4, 256, 0, stream>>>(xn32, g1, b1, wq_w, wq_b, ca_scale, kn, p_buf, tk_id);
    k_pv<<<dim3(B * N / 64, C / 64), 256, 0, stream>>>(p_buf, vvT, acc);
    k_gemm_fused<<<dim3(B * N / 64, NCAT / 96), 256, 0, stream>>>(xn, WcatT, bcat, qkv, hcat);
    k_sort_count<<<dim3(128, B), 128, 0, stream>>>(tk_id, ccnt);
    k_sort_scan<<<B, 128, 0, stream>>>(ccnt);
    k_sort_scatter<<<dim3(128, B), 128, 0, stream>>>(tk_id, ccnt, sidx);
    k_attn_mfma<<<dim3(NG, HEADS, B), 256, 0, stream>>>(qkv, sidx, o_bufp);
    k_gemm_big<C, 0><<<dim3(B * N / 128, C / 96), 256, 0, stream>>>(
        o_bufp, projT, proj_b, aca, nullptr);
    k_tdfill<<<(B * N * TDF + 255) / 256, 256, 0, stream>>>(tk_id, tdf, hcat);
    k_conv<<<dim3(64, 49, B), 256, 0, stream>>>(hcat, dw_w, dw_b, convsum);
    k_fc2ln<<<B * N / 32, 256, 0, stream>>>(convsum, fc2T, fc2_b, g3, b3, acc, aca, out);
}

// Round 23
// 368.307 us; speedup vs baseline: 1.0670x; 1.0670x over previous
//
#include <hip/hip_runtime.h>
#include <hip/hip_bf16.h>
#include <math.h>

using bf16 = __hip_bfloat16;

static constexpr int B = 2, C = 192, Hh = 128, Ww = 128, N = Hh * Ww;
static constexpr int M = 128, RD = 10, GS = 256, NG = N / GS;
static constexpr int HEADS = 4, HD = C / HEADS;                      // 48
static constexpr int TDF = 16, HID = 4 * C, HIDT = HID + TDF;        // 768, 784
static constexpr int TC3 = 3 * C;                                    // 576
static constexpr int NCAT = TC3 + HID;                               // 1344
static constexpr float LOG_M = 4.852030263919617f;                   // ln(128)
static constexpr float ATT_SCALE = 0.14433756729740643f;             // 48^-0.5

typedef __attribute__((ext_vector_type(8))) short bf16x8;
typedef __attribute__((ext_vector_type(4))) float f32x4;

__device__ __forceinline__ float b2f(bf16 v) { return __bfloat162float(v); }
__device__ __forceinline__ bf16 f2b(float v) { return __float2bfloat16(v); }
__device__ __forceinline__ float bits2f(unsigned short u) { return __uint_as_float(((unsigned)u) << 16); }
__device__ __forceinline__ unsigned short f2bits(float f) {
    union { bf16 h; unsigned short u; } cv; cv.h = f2b(f); return cv.u;
}
__device__ __forceinline__ float gelu_exact(float v) {
    return 0.5f * v * (1.0f + erff(v * 0.70710678118654752f));
}

// ---------- weight transpose+convert: in[K][Nn] f32 -> out[Nn][K] bf16 ----------
__global__ void __launch_bounds__(256) k_wtrans(const float* in, bf16* out, int K, int Nn) {
    __shared__ float T[64][65];
    int n0 = blockIdx.x * 64, k0 = blockIdx.y * 64;
    int tid = threadIdx.x;
    for (int e = tid; e < 4096; e += 256) {
        int kk = e >> 6, nn = e & 63;
        if (k0 + kk < K) T[kk][nn] = in[(size_t)(k0 + kk) * Nn + n0 + nn];
    }
    __syncthreads();
    for (int e = tid; e < 4096; e += 256) {
        int nn = e >> 6, kk = e & 63;
        if (k0 + kk < K) out[(size_t)(n0 + nn) * K + k0 + kk] = f2b(T[kk][nn]);
    }
}

// ---------- combined gain-folded weight prep: WcatT[n][k] = g[k]*W[k][n] ----------
__global__ void __launch_bounds__(256) k_wprep(const float* wqkv_w, const float* fc1_w,
                                               const float* g1, const float* g2, bf16* WcatT) {
    __shared__ float T[192 * 65];
    __shared__ float gl[192];
    int n0 = blockIdx.x * 64;
    int tid = threadIdx.x;
    bool isq = (n0 < TC3);
    const float* W = isq ? wqkv_w : fc1_w;
    const float* g = isq ? g1 : g2;
    int Nn = isq ? TC3 : HID;
    int nb = isq ? n0 : n0 - TC3;
    for (int k = tid; k < 192; k += 256) gl[k] = g[k];
    __syncthreads();
    for (int e = tid; e < 192 * 64; e += 256) {
        int k = e >> 6, nn = e & 63;
        T[k * 65 + nn] = W[(size_t)k * Nn + nb + nn] * gl[k];
    }
    __syncthreads();
    for (int e = tid; e < 64 * 192; e += 256) {
        int nn = e / 192, k = e % 192;
        WcatT[(size_t)(n0 + nn) * C + k] = f2b(T[k * 65 + nn]);
    }
}

// ---------- folded bias: bcat[n] = bias[n] + sum_k beta[k]*W[k][n] ----------
__global__ void k_bprep(const float* wqkv_w, const float* fc1_w, const float* wqkv_b,
                        const float* fc1_b, const float* b1, const float* b2v, float* bcat) {
    int n = blockIdx.x * 256 + threadIdx.x;
    if (n >= NCAT) return;
    float s;
    if (n < TC3) {
        s = wqkv_b[n];
        for (int k = 0; k < C; ++k) s += b1[k] * wqkv_w[(size_t)k * TC3 + n];
    } else {
        int nn = n - TC3;
        s = fc1_b[nn];
        for (int k = 0; k < C; ++k) s += b2v[k] * fc1_w[(size_t)k * HID + nn];
    }
    bcat[n] = s;
}

// ---------- K0: token-dict precompute: kn, vvT (bf16), td_feat ----------
__global__ void k_precompute(const float* td, const float* wk_w, const float* wk_b,
                             const float* wv_w, const float* wv_b,
                             const float* fc_td_w, const float* fc_td_b,
                             float* kn, bf16* vvT, float* tdf) {
    int m = blockIdx.x;
    int lane = threadIdx.x;      // 64
    __shared__ float trow[C];
    for (int ch = lane; ch < C; ch += 64) trow[ch] = td[m * C + ch];
    __syncthreads();
    __shared__ float ks[RD];
    __shared__ float inv_s;
    if (lane < RD) {
        float s = wk_b[lane];
        for (int ch = 0; ch < C; ++ch) s += trow[ch] * wk_w[ch * RD + lane];
        ks[lane] = s;
    }
    __syncthreads();
    if (lane == 0) {
        float ss = 0.f;
        for (int r = 0; r < RD; ++r) ss += ks[r] * ks[r];
        inv_s = 1.0f / fmaxf(sqrtf(ss), 1e-12f);
    }
    __syncthreads();
    if (lane < RD) kn[m * RD + lane] = ks[lane] * inv_s;
    for (int c0 = 0; c0 < 3; ++c0) {
        int co = lane + 64 * c0;
        float s = wv_b[co];
        for (int ch = 0; ch < C; ++ch) s += trow[ch] * wv_w[ch * C + co];
        vvT[(size_t)co * M + m] = f2b(s);
    }
    if (lane < TDF) {
        float s = fc_td_b[lane];
        for (int ch = 0; ch < C; ++ch) s += trow[ch] * fc_td_w[ch * TDF + lane];
        tdf[m * TDF + lane] = s;
    }
}

// ---------- K1: LN core via LDS transpose: xn (bf16, no gains), xn32, acc(fp32)=x ----------
__global__ void __launch_bounds__(256) k_ln(const float* x, bf16* xn, float* xn32, float* acc) {
    __shared__ float Xs[64 * 193];
    __shared__ float mu_s[64], rs_s[64];
    int tid = threadIdx.x;
    int m0 = blockIdx.x * 64;
    int b = m0 / N, i0 = m0 % N;
    for (int e = tid; e < 192 * 64; e += 256) {
        int ch = e >> 6, ii = e & 63;
        Xs[ii * 193 + ch] = x[((size_t)b * C + ch) * N + i0 + ii];
    }
    __syncthreads();
    {
        int tok = tid >> 2, part = tid & 3;
        float s = 0.f, ss = 0.f;
        for (int ch = part * 48; ch < part * 48 + 48; ++ch) {
            float v = Xs[tok * 193 + ch]; s += v; ss += v * v;
        }
        s += __shfl_xor(s, 1); ss += __shfl_xor(ss, 1);
        s += __shfl_xor(s, 2); ss += __shfl_xor(ss, 2);
        if (part == 0) {
            float mu = s / C;
            mu_s[tok] = mu;
            rs_s[tok] = rsqrtf(ss / C - mu * mu + 1e-5f);
        }
    }
    __syncthreads();
    for (int e = tid; e < 64 * 192; e += 256) {
        int ii = e / 192, ch = e % 192;
        float v = Xs[ii * 193 + ch];
        float xnv = (v - mu_s[ii]) * rs_s[ii];
        size_t g = (size_t)(m0 + ii);
        xn[g * C + ch] = f2b(xnv);
        xn32[g * C + ch] = xnv;
        acc[g * C + ch] = v;
    }
}

// ---------- K2: ATD_CA front-end ----------
__global__ void __launch_bounds__(256) k_atdca(const float* xn32, const float* g1, const float* b1,
                        const float* wq_w, const float* wq_b, const float* ca_scale,
                        const float* kn, bf16* p_buf, int* tk_id) {
    int t0 = blockIdx.x * 4;
    int w = threadIdx.x >> 6, lane = threadIdx.x & 63;
    int g = t0 + w;
    float xn[3];
    #pragma unroll
    for (int k = 0; k < 3; ++k) {
        int ch = lane + 64 * k;
        xn[k] = xn32[(size_t)g * C + ch] * g1[ch] + b1[ch];
    }
    float q[RD];
    #pragma unroll
    for (int r = 0; r < RD; ++r) {
        float p = 0.f;
        #pragma unroll
        for (int k = 0; k < 3; ++k) { int ch = lane + 64 * k; p += xn[k] * wq_w[ch * RD + r]; }
        for (int mk = 32; mk >= 1; mk >>= 1) p += __shfl_xor(p, mk);
        q[r] = p + wq_b[r];
    }
    float ssn = 0.f;
    #pragma unroll
    for (int r = 0; r < RD; ++r) ssn += q[r] * q[r];
    float invq = 1.0f / fmaxf(sqrtf(ssn), 1e-12f);
    float s0 = 0.f, s1 = 0.f;
    #pragma unroll
    for (int r = 0; r < RD; ++r) {
        float qr = q[r] * invq;
        s0 += qr * kn[lane * RD + r];
        s1 += qr * kn[(lane + 64) * RD + r];
    }
    float mv; int mi;
    if (s1 > s0) { mv = s1; mi = lane + 64; } else { mv = s0; mi = lane; }
    for (int mk = 32; mk >= 1; mk >>= 1) {
        float ov = __shfl_xor(mv, mk); int oi = __shfl_xor(mi, mk);
        if (ov > mv || (ov == mv && oi < mi)) { mv = ov; mi = oi; }
    }
    float cs = ca_scale[0]; cs = fminf(fmaxf(cs, 0.0f), 3.0f);
    float scale = 1.0f + cs * LOG_M;
    float e0 = expf((s0 - mv) * scale), e1 = expf((s1 - mv) * scale);
    float sum = e0 + e1;
    for (int mk = 32; mk >= 1; mk >>= 1) sum += __shfl_xor(sum, mk);
    float invs = 1.0f / sum;
    p_buf[(size_t)g * M + lane] = f2b(e0 * invs);
    p_buf[(size_t)g * M + lane + 64] = f2b(e1 * invs);
    if (lane == 0) tk_id[g] = mi;
}

// ---------- K2b: acc += p_buf @ vvT  (MFMA GEMM, K=128, fp32 RMW) ----------
__global__ void __launch_bounds__(256) k_pv(const bf16* p_buf, const bf16* vvT, float* acc) {
    __shared__ __align__(16) short As[64 * 136];
    __shared__ __align__(16) short Bs[64 * 136];
    int tid = threadIdx.x;
    int m0 = blockIdx.x * 64;
    int n0 = blockIdx.y * 64;
    for (int e = tid; e < 64 * 16; e += 256) {
        int m = e >> 4, kc = (e & 15) * 8;
        *(uint4*)&As[m * 136 + kc] = *(const uint4*)(p_buf + (size_t)(m0 + m) * M + kc);
    }
    for (int e = tid; e < 64 * 16; e += 256) {
        int n = e >> 4, kc = (e & 15) * 8;
        *(uint4*)&Bs[n * 136 + kc] = *(const uint4*)(vvT + (size_t)(n0 + n) * M + kc);
    }
    __syncthreads();
    int w = tid >> 6, lane = tid & 63;
    int wm = (w >> 1) * 32, wn = (w & 1) * 32;
    int lr = lane & 15, lk = (lane >> 4) * 8;
    f32x4 acc00 = {0.f,0.f,0.f,0.f}, acc01 = acc00, acc10 = acc00, acc11 = acc00;
    #pragma unroll
    for (int ks = 0; ks < 4; ++ks) {
        int k0 = ks * 32 + lk;
        bf16x8 a0 = *(bf16x8*)&As[(wm + lr) * 136 + k0];
        bf16x8 a1 = *(bf16x8*)&As[(wm + 16 + lr) * 136 + k0];
        bf16x8 b0 = *(bf16x8*)&Bs[(wn + lr) * 136 + k0];
        bf16x8 b1 = *(bf16x8*)&Bs[(wn + 16 + lr) * 136 + k0];
        acc00 = __builtin_amdgcn_mfma_f32_16x16x32_bf16(a0, b0, acc00, 0, 0, 0);
        acc01 = __builtin_amdgcn_mfma_f32_16x16x32_bf16(a0, b1, acc01, 0, 0, 0);
        acc10 = __builtin_amdgcn_mfma_f32_16x16x32_bf16(a1, b0, acc10, 0, 0, 0);
        acc11 = __builtin_amdgcn_mfma_f32_16x16x32_bf16(a1, b1, acc11, 0, 0, 0);
    }
    int rbase = (lane >> 4) * 4;
    f32x4 accs[2][2] = {{acc00, acc01}, {acc10, acc11}};
    #pragma unroll
    for (int mt = 0; mt < 2; ++mt) {
        #pragma unroll
        for (int nt = 0; nt < 2; ++nt) {
            int co = n0 + wn + nt * 16 + lr;
            #pragma unroll
            for (int r = 0; r < 4; ++r) {
                int tok = m0 + wm + mt * 16 + rbase + r;
                acc[(size_t)tok * C + co] += accs[mt][nt][r];
            }
        }
    }
}

// ---------- fused qkv+fc1 GEMM with LDS-coalesced epilogue ----------
__global__ void __launch_bounds__(256) k_gemm_fused(const bf16* Abuf, const bf16* Wt, const float* bias,
                                                    bf16* qkv, bf16* hcat) {
    __shared__ __align__(16) unsigned short As[128 * 104];
    __shared__ __align__(16) unsigned short Bs[96 * 104];
    int tid = threadIdx.x;
    int m0 = blockIdx.x * 128, n0 = blockIdx.y * 96;
    int w = tid >> 6, lane = tid & 63;
    int wm = (w >> 1) * 64, wn = (w & 1) * 48;
    int lr = lane & 15, g8 = lane >> 4;
    f32x4 acc[4][3];
    #pragma unroll
    for (int mt = 0; mt < 4; ++mt)
        #pragma unroll
        for (int nt = 0; nt < 3; ++nt) acc[mt][nt] = (f32x4){0.f,0.f,0.f,0.f};
    for (int kc = 0; kc < 2; ++kc) {
        int kb = kc * 96;
        __syncthreads();
        for (int e = tid; e < 128 * 12; e += 256) {
            int m = e / 12, blk = e % 12;
            *(uint4*)&As[m * 104 + blk * 8] = *(const uint4*)(Abuf + (size_t)(m0 + m) * C + kb + blk * 8);
        }
        for (int e = tid; e < 96 * 12; e += 256) {
            int n = e / 12, blk = e % 12;
            *(uint4*)&Bs[n * 104 + blk * 8] = *(const uint4*)(Wt + (size_t)(n0 + n) * C + kb + blk * 8);
        }
        __syncthreads();
        #pragma unroll
        for (int ks = 0; ks < 3; ++ks) {
            int blk = ks * 4 + g8;
            bf16x8 a[4];
            bf16x8 bfr[3];
            #pragma unroll
            for (int mt = 0; mt < 4; ++mt) a[mt] = *(bf16x8*)&As[(wm + mt * 16 + lr) * 104 + blk * 8];
            #pragma unroll
            for (int nt = 0; nt < 3; ++nt) bfr[nt] = *(bf16x8*)&Bs[(wn + nt * 16 + lr) * 104 + blk * 8];
            #pragma unroll
            for (int mt = 0; mt < 4; ++mt)
                #pragma unroll
                for (int nt = 0; nt < 3; ++nt)
                    acc[mt][nt] = __builtin_amdgcn_mfma_f32_16x16x32_bf16(a[mt], bfr[nt], acc[mt][nt], 0, 0, 0);
        }
    }
    bool isq = (n0 < TC3);
    __syncthreads();                               // all ds_reads done; reuse As as output tile
    #pragma unroll
    for (int nt = 0; nt < 3; ++nt) {
        int col = wn + nt * 16 + lr;
        float bv = bias[n0 + col];
        #pragma unroll
        for (int mt = 0; mt < 4; ++mt) {
            #pragma unroll
            for (int r = 0; r < 4; ++r) {
                int row = wm + mt * 16 + g8 * 4 + r;
                float v = acc[mt][nt][r] + bv;
                As[row * 104 + col] = f2bits(isq ? v : gelu_exact(v));
            }
        }
    }
    __syncthreads();
    // coalesced store: 128 rows x 12 uint4 (192 B/row)
    if (isq) {
        for (int e = tid; e < 128 * 12; e += 256) {
            int row = e / 12, blk = e % 12;
            *(uint4*)(qkv + (size_t)(m0 + row) * TC3 + n0 + blk * 8) = *(uint4*)&As[row * 104 + blk * 8];
        }
    } else {
        int nh = n0 - TC3;
        for (int e = tid; e < 128 * 12; e += 256) {
            int row = e / 12, blk = e % 12;
            *(uint4*)(hcat + (size_t)(m0 + row) * HIDT + nh + blk * 8) = *(uint4*)&As[row * 104 + blk * 8];
        }
    }
}

// ---------- K3: MFMA GEMM, tile 128x96, K=192 (proj) ----------
template<int OUTLD, int MODE>
__global__ void __launch_bounds__(256) k_gemm_big(const bf16* Abuf, const bf16* Wt, const float* bias,
                                                  bf16* outb, float* outf) {
    __shared__ __align__(16) unsigned short As[128 * 104];
    __shared__ __align__(16) unsigned short Bs[96 * 104];
    int tid = threadIdx.x;
    int m0 = blockIdx.x * 128, n0 = blockIdx.y * 96;
    int w = tid >> 6, lane = tid & 63;
    int wm = (w >> 1) * 64, wn = (w & 1) * 48;
    int lr = lane & 15, g8 = lane >> 4;
    f32x4 acc[4][3];
    #pragma unroll
    for (int mt = 0; mt < 4; ++mt)
        #pragma unroll
        for (int nt = 0; nt < 3; ++nt) acc[mt][nt] = (f32x4){0.f,0.f,0.f,0.f};
    for (int kc = 0; kc < 2; ++kc) {
        int kb = kc * 96;
        __syncthreads();
        for (int e = tid; e < 128 * 12; e += 256) {
            int m = e / 12, blk = e % 12;
            *(uint4*)&As[m * 104 + blk * 8] = *(const uint4*)(Abuf + (size_t)(m0 + m) * C + kb + blk * 8);
        }
        for (int e = tid; e < 96 * 12; e += 256) {
            int n = e / 12, blk = e % 12;
            *(uint4*)&Bs[n * 104 + blk * 8] = *(const uint4*)(Wt + (size_t)(n0 + n) * C + kb + blk * 8);
        }
        __syncthreads();
        #pragma unroll
        for (int ks = 0; ks < 3; ++ks) {
            int blk = ks * 4 + g8;
            bf16x8 a[4];
            bf16x8 bfr[3];
            #pragma unroll
            for (int mt = 0; mt < 4; ++mt) a[mt] = *(bf16x8*)&As[(wm + mt * 16 + lr) * 104 + blk * 8];
            #pragma unroll
            for (int nt = 0; nt < 3; ++nt) bfr[nt] = *(bf16x8*)&Bs[(wn + nt * 16 + lr) * 104 + blk * 8];
            #pragma unroll
            for (int mt = 0; mt < 4; ++mt)
                #pragma unroll
                for (int nt = 0; nt < 3; ++nt)
                    acc[mt][nt] = __builtin_amdgcn_mfma_f32_16x16x32_bf16(a[mt], bfr[nt], acc[mt][nt], 0, 0, 0);
        }
    }
    __syncthreads();
    #pragma unroll
    for (int nt = 0; nt < 3; ++nt) {
        int col = wn + nt * 16 + lr;
        float bv = bias[n0 + col];
        #pragma unroll
        for (int mt = 0; mt < 4; ++mt) {
            #pragma unroll
            for (int r = 0; r < 4; ++r) {
                int row = wm + mt * 16 + g8 * 4 + r;
                float v = acc[mt][nt][r] + bv;
                As[row * 104 + col] = f2bits(MODE == 1 ? gelu_exact(v) : v);
            }
        }
    }
    __syncthreads();
    for (int e = tid; e < 128 * 12; e += 256) {
        int row = e / 12, blk = e % 12;
        *(uint4*)(outb + (size_t)(m0 + row) * OUTLD + n0 + blk * 8) = *(uint4*)&As[row * 104 + blk * 8];
    }
}

// ---------- Stable counting sort by tk_id ----------
__global__ void k_sort_count(const int* tk_id, int* chunk_cnt) {
    int c = blockIdx.x, b = blockIdx.y;
    int tid = threadIdx.x;               // 128
    __shared__ int cnt[M];
    cnt[tid] = 0;
    __syncthreads();
    atomicAdd(&cnt[tk_id[b * N + c * 128 + tid]], 1);
    __syncthreads();
    chunk_cnt[(b * 128 + c) * M + tid] = cnt[tid];
}

__global__ void k_sort_scan(int* chunk_cnt) {
    int b = blockIdx.x;
    int k = threadIdx.x;
    int tot = 0;
    for (int c = 0; c < 128; ++c) tot += chunk_cnt[(b * 128 + c) * M + k];
    __shared__ int totals[M];
    __shared__ int base[M];
    totals[k] = tot;
    __syncthreads();
    if (k == 0) {
        int run = 0;
        for (int kk = 0; kk < M; ++kk) { base[kk] = run; run += totals[kk]; }
    }
    __syncthreads();
    int run = base[k];
    for (int c = 0; c < 128; ++c) {
        int v = chunk_cnt[(b * 128 + c) * M + k];
        chunk_cnt[(b * 128 + c) * M + k] = run;
        run += v;
    }
}

__global__ void k_sort_scatter(const int* tk_id, const int* chunk_cnt, int* sort_idx) {
    int c = blockIdx.x, b = blockIdx.y;
    int k = threadIdx.x;
    __shared__ int keys[128];
    keys[k] = tk_id[b * N + c * 128 + k];
    __syncthreads();
    int off = chunk_cnt[(b * 128 + c) * M + k];
    for (int j = 0; j < 128; ++j) {
        if (keys[j] == k) sort_idx[b * N + off++] = c * 128 + j;
    }
}

// ---------- MFMA grouped self-attention: block = (group, head, batch) ----------
__global__ void __launch_bounds__(256) k_attn_mfma(const bf16* qkv, const int* sort_idx, bf16* o_buf) {
    int g = blockIdx.x, h = blockIdx.y, b = blockIdx.z;
    __shared__ int sidx[GS];
    __shared__ __align__(16) unsigned short Kl[256 * 64];
    __shared__ __align__(16) unsigned short Vt[48 * 256];
    __shared__ __align__(16) unsigned short Pl[4][64 * 32];
    int tid = threadIdx.x;
    sidx[tid] = sort_idx[b * N + g * GS + tid];
    __syncthreads();
    {
        int row = tid;
        int srow = sidx[row];
        size_t kb = ((size_t)(b * N + srow)) * TC3 + C + h * HD;
        size_t vb = ((size_t)(b * N + srow)) * TC3 + 2 * C + h * HD;
        #pragma unroll
        for (int db = 0; db < 6; ++db) {
            uint4 kv = *(const uint4*)(qkv + kb + db * 8);
            *(uint4*)&Kl[row * 64 + ((db ^ (row & 7)) * 8)] = kv;
            uint4 vv4 = *(const uint4*)(qkv + vb + db * 8);
            unsigned short* vu = (unsigned short*)&vv4;
            #pragma unroll
            for (int j = 0; j < 8; ++j) {
                int d = db * 8 + j;
                Vt[d * 256 + (((row >> 3) ^ (d & 7)) * 8) + (row & 7)] = vu[j];
            }
        }
        uint4 z = {0u,0u,0u,0u};
        *(uint4*)&Kl[row * 64 + ((6 ^ (row & 7)) * 8)] = z;
        *(uint4*)&Kl[row * 64 + ((7 ^ (row & 7)) * 8)] = z;
    }
    __syncthreads();
    int w = tid >> 6, l = tid & 63;
    int lq = l & 15, g8 = l >> 4;
    bf16x8 qf[4][2];
    #pragma unroll
    for (int qt = 0; qt < 4; ++qt) {
        int qrow = sidx[w * 64 + qt * 16 + lq];
        size_t qb = ((size_t)(b * N + qrow)) * TC3 + h * HD;
        qf[qt][0] = *(const bf16x8*)(qkv + qb + g8 * 8);
        int d1 = 32 + g8 * 8;
        if (d1 < HD) qf[qt][1] = *(const bf16x8*)(qkv + qb + d1);
        else { uint4 z = {0u,0u,0u,0u}; qf[qt][1] = *(bf16x8*)&z; }
    }
    float mrun[4], lrun[4];
    f32x4 Oa[4][3];
    #pragma unroll
    for (int qt = 0; qt < 4; ++qt) {
        mrun[qt] = -1e30f; lrun[qt] = 0.f;
        #pragma unroll
        for (int dt = 0; dt < 3; ++dt) Oa[qt][dt] = (f32x4){0.f,0.f,0.f,0.f};
    }
    unsigned short* Pw = &Pl[w][0];
    for (int ck = 0; ck < 8; ++ck) {
        int kbase = ck * 32;
        bf16x8 kf[2][2];
        #pragma unroll
        for (int kt = 0; kt < 2; ++kt) {
            int key = kbase + kt * 16 + lq;
            #pragma unroll
            for (int ks = 0; ks < 2; ++ks)
                kf[kt][ks] = *(bf16x8*)&Kl[key * 64 + (((ks * 4 + g8) ^ (key & 7)) * 8)];
        }
        bf16x8 vf[3];
        #pragma unroll
        for (int dt = 0; dt < 3; ++dt) {
            int d = dt * 16 + lq;
            vf[dt] = *(bf16x8*)&Vt[d * 256 + ((((kbase >> 3) + g8) ^ (d & 7)) * 8)];
        }
        #pragma unroll
        for (int qt = 0; qt < 4; ++qt) {
            f32x4 s0 = {0.f,0.f,0.f,0.f}, s1 = s0;
            s0 = __builtin_amdgcn_mfma_f32_16x16x32_bf16(kf[0][0], qf[qt][0], s0, 0, 0, 0);
            s0 = __builtin_amdgcn_mfma_f32_16x16x32_bf16(kf[0][1], qf[qt][1], s0, 0, 0, 0);
            s1 = __builtin_amdgcn_mfma_f32_16x16x32_bf16(kf[1][0], qf[qt][0], s1, 0, 0, 0);
            s1 = __builtin_amdgcn_mfma_f32_16x16x32_bf16(kf[1][1], qf[qt][1], s1, 0, 0, 0);
            float sv0[4], sv1[4];
            float cmax = -1e30f;
            #pragma unroll
            for (int r = 0; r < 4; ++r) {
                sv0[r] = s0[r] * ATT_SCALE; sv1[r] = s1[r] * ATT_SCALE;
                cmax = fmaxf(cmax, fmaxf(sv0[r], sv1[r]));
            }
            cmax = fmaxf(cmax, __shfl_xor(cmax, 16));
            cmax = fmaxf(cmax, __shfl_xor(cmax, 32));
            float mnew = fmaxf(mrun[qt], cmax);
            float sf = expf(mrun[qt] - mnew);
            float p0[4], p1[4], csum = 0.f;
            #pragma unroll
            for (int r = 0; r < 4; ++r) {
                p0[r] = expf(sv0[r] - mnew); p1[r] = expf(sv1[r] - mnew);
                csum += p0[r] + p1[r];
            }
            csum += __shfl_xor(csum, 16);
            csum += __shfl_xor(csum, 32);
            lrun[qt] = lrun[qt] * sf + csum;
            mrun[qt] = mnew;
            int q = qt * 16 + lq;
            {
                unsigned short pw[4];
                #pragma unroll
                for (int r = 0; r < 4; ++r) pw[r] = f2bits(p0[r]);
                int slot = g8;
                int addr = q * 32 + (((slot >> 1) ^ (q & 3)) * 8) + (slot & 1) * 4;
                *(uint2*)&Pw[addr] = *(uint2*)pw;
                #pragma unroll
                for (int r = 0; r < 4; ++r) pw[r] = f2bits(p1[r]);
                slot = 4 + g8;
                addr = q * 32 + (((slot >> 1) ^ (q & 3)) * 8) + (slot & 1) * 4;
                *(uint2*)&Pw[addr] = *(uint2*)pw;
            }
            float sfr[4];
            #pragma unroll
            for (int r = 0; r < 4; ++r) sfr[r] = __shfl(sf, 4 * g8 + r);
            #pragma unroll
            for (int dt = 0; dt < 3; ++dt)
                #pragma unroll
                for (int r = 0; r < 4; ++r) Oa[qt][dt][r] *= sfr[r];
            bf16x8 pa = *(bf16x8*)&Pw[q * 32 + ((g8 ^ (lq & 3)) * 8)];
            #pragma unroll
            for (int dt = 0; dt < 3; ++dt)
                Oa[qt][dt] = __builtin_amdgcn_mfma_f32_16x16x32_bf16(pa, vf[dt], Oa[qt][dt], 0, 0, 0);
        }
    }
    #pragma unroll
    for (int qt = 0; qt < 4; ++qt) {
        float invq = 1.0f / lrun[qt];
        float invr[4];
        #pragma unroll
        for (int r = 0; r < 4; ++r) invr[r] = __shfl(invq, 4 * g8 + r);
        #pragma unroll
        for (int r = 0; r < 4; ++r) {
            int grow = sidx[w * 64 + qt * 16 + 4 * g8 + r];
            size_t obase = ((size_t)(b * N + grow)) * C + h * HD;
            #pragma unroll
            for (int dt = 0; dt < 3; ++dt)
                o_buf[obase + dt * 16 + lq] = f2b(Oa[qt][dt][r] * invr[r]);
        }
    }
}

// ---------- td feature gather into hcat tail columns ----------
__global__ void k_tdfill(const int* tk_id, const float* tdf, bf16* hcat) {
    int idx = blockIdx.x * 256 + threadIdx.x;
    if (idx >= B * N * TDF) return;
    int tok = idx >> 4, f = idx & 15;
    hcat[(size_t)tok * HIDT + HID + f] = f2b(tdf[tk_id[tok] * TDF + f]);
}

// ---------- depthwise 5x5 conv v5b: fp32 LDS tile, unroll-1 ky loop ----------
__global__ void __launch_bounds__(256) k_conv(const bf16* hcat, const float* dw_w, const float* dw_b,
                                              bf16* convsum) {
    int st = blockIdx.x;
    int c16 = blockIdx.y;
    int b = blockIdx.z;
    int tx0 = (st & 7) * 16, ty0 = (st >> 3) * 16;
    int tid = threadIdx.x;
    __shared__ __align__(16) float Hf[20 * 81 * 4];
    __shared__ __align__(16) float Wf[25 * 16];
    __shared__ float Wb[16];
    for (int e = tid; e < 400; e += 256) {
        int tap = e >> 4, ch = e & 15;
        Wf[e] = dw_w[(size_t)(c16 * 16 + ch) * 25 + tap];
    }
    if (tid < 16) Wb[tid] = dw_b[c16 * 16 + tid];
    for (int e = tid; e < 800; e += 256) {
        int pos = e >> 1, sc = e & 1;
        int py = pos / 20, px = pos % 20;
        int gy = ty0 + py - 2, gx = tx0 + px - 2;
        uint4 v = {0u, 0u, 0u, 0u};
        if (gy >= 0 && gy < Hh && gx >= 0 && gx < Ww)
            v = *(const uint4*)(hcat + ((size_t)b * N + gy * Ww + gx) * HIDT + c16 * 16 + sc * 8);
        unsigned short* u = (unsigned short*)&v;
        float4 f0 = { bits2f(u[0]), bits2f(u[1]), bits2f(u[2]), bits2f(u[3]) };
        float4 f1 = { bits2f(u[4]), bits2f(u[5]), bits2f(u[6]), bits2f(u[7]) };
        int base = (py * 81 + px * 4 + sc * 2) * 4;
        *(float4*)&Hf[base] = f0;
        *(float4*)&Hf[base + 4] = f1;
    }
    __syncthreads();
    int cc = tid & 1, lx = (tid >> 1) & 7, ly = tid >> 4;
    float acc[2][8] = {};
    #pragma unroll 1
    for (int ky = 0; ky < 5; ++ky) {
        int py = ly + ky;
        float4 w[5][2];
        #pragma unroll
        for (int kx = 0; kx < 5; ++kx) {
            w[kx][0] = *(float4*)&Wf[(ky * 5 + kx) * 16 + cc * 8];
            w[kx][1] = *(float4*)&Wf[(ky * 5 + kx) * 16 + cc * 8 + 4];
        }
        #pragma unroll
        for (int c = 0; c < 6; ++c) {
            int px = 2 * lx + c;
            int base = (py * 81 + px * 4 + cc * 2) * 4;
            float4 f0 = *(float4*)&Hf[base];
            float4 f1 = *(float4*)&Hf[base + 4];
            float f[8] = { f0.x, f0.y, f0.z, f0.w, f1.x, f1.y, f1.z, f1.w };
            #pragma unroll
            for (int kx = 0; kx < 5; ++kx) {
                int ox = c - kx;
                if (ox >= 0 && ox < 2) {
                    const float* wp = (const float*)&w[kx][0];
                    #pragma unroll
                    for (int j = 0; j < 8; ++j) acc[ox][j] += f[j] * wp[j];
                }
            }
        }
    }
    int gy = ty0 + ly;
    #pragma unroll
    for (int ox = 0; ox < 2; ++ox) {
        int px = 2 * lx + ox + 2, py = ly + 2;
        int base = (py * 81 + px * 4 + cc * 2) * 4;
        float4 f0 = *(float4*)&Hf[base];
        float4 f1 = *(float4*)&Hf[base + 4];
        float cf[8] = { f0.x, f0.y, f0.z, f0.w, f1.x, f1.y, f1.z, f1.w };
        unsigned short ow[8];
        #pragma unroll
        for (int j = 0; j < 8; ++j)
            ow[j] = f2bits(cf[j] + gelu_exact(acc[ox][j] + Wb[cc * 8 + j]));
        int gx = tx0 + 2 * lx + ox;
        *(uint4*)(convsum + ((size_t)b * N + gy * Ww + gx) * HIDT + c16 * 16 + cc * 8) = *(uint4*)ow;
    }
}

// ---------- fc2 (K=784) MFMA v4: direct register GEMM; accres fp32 + aca bf16 ----------
__global__ void __launch_bounds__(256) k_fc2ln(const bf16* convsum, const bf16* Wt,
                                               const float* bias, const float* g3, const float* b3,
                                               const float* accres, const bf16* aca, float* out) {
    __shared__ float Ot[192 * 36];
    __shared__ float partS[4][32], partQ[4][32];
    int tid = threadIdx.x;
    int m0 = blockIdx.x * 32;
    int w = tid >> 6, lane = tid & 63;
    int lr = lane & 15, g8 = lane >> 4;
    int n0 = w * 48;
    f32x4 acc[2][3];
    #pragma unroll
    for (int mt = 0; mt < 2; ++mt)
        #pragma unroll
        for (int nt = 0; nt < 3; ++nt) acc[mt][nt] = (f32x4){0.f,0.f,0.f,0.f};
    const bf16* a0p = convsum + (size_t)(m0 + lr) * HIDT + g8 * 8;
    const bf16* a1p = convsum + (size_t)(m0 + 16 + lr) * HIDT + g8 * 8;
    const bf16* b0p = Wt + (size_t)(n0 + lr) * HIDT + g8 * 8;
    const bf16* b1p = Wt + (size_t)(n0 + 16 + lr) * HIDT + g8 * 8;
    const bf16* b2p = Wt + (size_t)(n0 + 32 + lr) * HIDT + g8 * 8;
    #pragma unroll 4
    for (int kk = 0; kk < 24; ++kk) {
        int k0 = kk * 32;
        bf16x8 a0 = *(const bf16x8*)(a0p + k0);
        bf16x8 a1 = *(const bf16x8*)(a1p + k0);
        bf16x8 w0 = *(const bf16x8*)(b0p + k0);
        bf16x8 w1 = *(const bf16x8*)(b1p + k0);
        bf16x8 w2 = *(const bf16x8*)(b2p + k0);
        acc[0][0] = __builtin_amdgcn_mfma_f32_16x16x32_bf16(a0, w0, acc[0][0], 0, 0, 0);
        acc[0][1] = __builtin_amdgcn_mfma_f32_16x16x32_bf16(a0, w1, acc[0][1], 0, 0, 0);
        acc[0][2] = __builtin_amdgcn_mfma_f32_16x16x32_bf16(a0, w2, acc[0][2], 0, 0, 0);
        acc[1][0] = __builtin_amdgcn_mfma_f32_16x16x32_bf16(a1, w0, acc[1][0], 0, 0, 0);
        acc[1][1] = __builtin_amdgcn_mfma_f32_16x16x32_bf16(a1, w1, acc[1][1], 0, 0, 0);
        acc[1][2] = __builtin_amdgcn_mfma_f32_16x16x32_bf16(a1, w2, acc[1][2], 0, 0, 0);
    }
    {
        uint4 z = {0u,0u,0u,0u};
        bf16x8 a0 = *(bf16x8*)&z, a1 = a0, w0 = a0, w1 = a0, w2 = a0;
        if (g8 < 2) {
            a0 = *(const bf16x8*)(a0p + 768);
            a1 = *(const bf16x8*)(a1p + 768);
            w0 = *(const bf16x8*)(b0p + 768);
            w1 = *(const bf16x8*)(b1p + 768);
            w2 = *(const bf16x8*)(b2p + 768);
        }
        acc[0][0] = __builtin_amdgcn_mfma_f32_16x16x32_bf16(a0, w0, acc[0][0], 0, 0, 0);
        acc[0][1] = __builtin_amdgcn_mfma_f32_16x16x32_bf16(a0, w1, acc[0][1], 0, 0, 0);
        acc[0][2] = __builtin_amdgcn_mfma_f32_16x16x32_bf16(a0, w2, acc[0][2], 0, 0, 0);
        acc[1][0] = __builtin_amdgcn_mfma_f32_16x16x32_bf16(a1, w0, acc[1][0], 0, 0, 0);
        acc[1][1] = __builtin_amdgcn_mfma_f32_16x16x32_bf16(a1, w1, acc[1][1], 0, 0, 0);
        acc[1][2] = __builtin_amdgcn_mfma_f32_16x16x32_bf16(a1, w2, acc[1][2], 0, 0, 0);
    }
    #pragma unroll
    for (int nt = 0; nt < 3; ++nt) {
        float bv = bias[n0 + nt * 16 + lr];
        #pragma unroll
        for (int mt = 0; mt < 2; ++mt)
            #pragma unroll
            for (int r = 0; r < 4; ++r) acc[mt][nt][r] += bv;
    }
    #pragma unroll
    for (int mt = 0; mt < 2; ++mt) {
        #pragma unroll
        for (int r = 0; r < 4; ++r) {
            float s = 0.f, q = 0.f;
            #pragma unroll
            for (int nt = 0; nt < 3; ++nt) { float v = acc[mt][nt][r]; s += v; q += v * v; }
            s += __shfl_xor(s, 1); q += __shfl_xor(q, 1);
            s += __shfl_xor(s, 2); q += __shfl_xor(q, 2);
            s += __shfl_xor(s, 4); q += __shfl_xor(q, 4);
            s += __shfl_xor(s, 8); q += __shfl_xor(q, 8);
            if (lr == 0) {
                int row = mt * 16 + g8 * 4 + r;
                partS[w][row] = s;
                partQ[w][row] = q;
            }
        }
    }
    __syncthreads();
    int bb = m0 / N, i0 = m0 % N;
    #pragma unroll
    for (int mt = 0; mt < 2; ++mt) {
        #pragma unroll
        for (int r = 0; r < 4; ++r) {
            int row = mt * 16 + g8 * 4 + r;
            float s = partS[0][row] + partS[1][row] + partS[2][row] + partS[3][row];
            float q = partQ[0][row] + partQ[1][row] + partQ[2][row] + partQ[3][row];
            float mu = s / C;
            float rstd = rsqrtf(q / C - mu * mu + 1e-5f);
            int tok = m0 + row;
            #pragma unroll
            for (int nt = 0; nt < 3; ++nt) {
                int c = n0 + nt * 16 + lr;
                float o = accres[(size_t)tok * C + c] + b2f(aca[(size_t)tok * C + c])
                        + (acc[mt][nt][r] - mu) * rstd * g3[c] + b3[c];
                Ot[c * 36 + row] = o;
            }
        }
    }
    __syncthreads();
    for (int e = tid; e < 192 * 8; e += 256) {
        int row = e >> 3, q4 = e & 7;
        float4 v = *(float4*)&Ot[row * 36 + q4 * 4];
        *(float4*)(out + ((size_t)(bb * C + row)) * N + i0 + q4 * 4) = v;
    }
}

__global__ void k_sentinel(float* out, int nelem) {
    int i = blockIdx.x * blockDim.x + threadIdx.x;
    if (i < nelem) out[i] = 1234.0f;
}

extern "C" void kernel_launch(void* const* d_in, const int* in_sizes, int n_in,
                              void* d_out, int out_size, void* d_ws, size_t ws_size,
                              hipStream_t stream) {
    const float* x        = (const float*)d_in[0];
    const float* td       = (const float*)d_in[2];
    const float* g1       = (const float*)d_in[3];
    const float* b1       = (const float*)d_in[4];
    const float* g2       = (const float*)d_in[5];
    const float* b2v      = (const float*)d_in[6];
    const float* g3       = (const float*)d_in[7];
    const float* b3       = (const float*)d_in[8];
    const float* wq_w     = (const float*)d_in[9];
    const float* wq_b     = (const float*)d_in[10];
    const float* wk_w     = (const float*)d_in[11];
    const float* wk_b     = (const float*)d_in[12];
    const float* wv_w     = (const float*)d_in[13];
    const float* wv_b     = (const float*)d_in[14];
    const float* ca_scale = (const float*)d_in[15];
    const float* wqkv_w   = (const float*)d_in[16];
    const float* wqkv_b   = (const float*)d_in[17];
    const float* proj_w   = (const float*)d_in[18];
    const float* proj_b   = (const float*)d_in[19];
    const float* fc_td_w  = (const float*)d_in[20];
    const float* fc_td_b  = (const float*)d_in[21];
    const float* fc1_w    = (const float*)d_in[22];
    const float* fc1_b    = (const float*)d_in[23];
    const float* dw_w     = (const float*)d_in[24];
    const float* dw_b     = (const float*)d_in[25];
    const float* fc2_w    = (const float*)d_in[26];
    const float* fc2_b    = (const float*)d_in[27];
    float* out = (float*)d_out;

    char* ws = (char*)d_ws;
    size_t off = 0;
    auto alloc = [&](size_t bytes) { size_t o = off; off += (bytes + 255) & ~(size_t)255; return o; };
    size_t o_xn    = alloc((size_t)B * N * C * 2);
    size_t o_xn32  = alloc((size_t)B * N * C * 4);
    size_t o_acc   = alloc((size_t)B * N * C * 4);
    size_t o_aca   = alloc((size_t)B * N * C * 2);
    size_t o_qkv   = alloc((size_t)B * N * TC3 * 2);
    size_t o_hcat  = alloc((size_t)B * N * HIDT * 2);
    size_t o_conv  = alloc((size_t)B * N * HIDT * 2);
    size_t o_obuf  = alloc((size_t)B * N * C * 2);
    size_t o_kn    = alloc((size_t)M * RD * 4);
    size_t o_vvT   = alloc((size_t)C * M * 2);
    size_t o_tdf   = alloc((size_t)M * TDF * 4);
    size_t o_tk    = alloc((size_t)B * N * 4);
    size_t o_sidx  = alloc((size_t)B * N * 4);
    size_t o_ccnt  = alloc((size_t)B * 128 * M * 4);
    size_t o_pbuf  = alloc((size_t)B * N * M * 2);
    size_t o_wcat  = alloc((size_t)NCAT * C * 2);
    size_t o_bcat  = alloc((size_t)NCAT * 4);
    size_t o_projT = alloc((size_t)C * C * 2);
    size_t o_fc2T  = alloc((size_t)C * HIDT * 2);

    if (ws_size < off) {
        k_sentinel<<<(out_size + 255) / 256, 256, 0, stream>>>(out, out_size);
        return;
    }

    bf16*  xn      = (bf16*)(ws + o_xn);
    float* xn32    = (float*)(ws + o_xn32);
    float* acc     = (float*)(ws + o_acc);
    bf16*  aca     = (bf16*)(ws + o_aca);
    bf16*  qkv     = (bf16*)(ws + o_qkv);
    bf16*  hcat    = (bf16*)(ws + o_hcat);
    bf16*  convsum = (bf16*)(ws + o_conv);
    bf16*  o_bufp  = (bf16*)(ws + o_obuf);
    float* kn      = (float*)(ws + o_kn);
    bf16*  vvT     = (bf16*)(ws + o_vvT);
    float* tdf     = (float*)(ws + o_tdf);
    int*   tk_id   = (int*)(ws + o_tk);
    int*   sidx    = (int*)(ws + o_sidx);
    int*   ccnt    = (int*)(ws + o_ccnt);
    bf16*  p_buf   = (bf16*)(ws + o_pbuf);
    bf16*  WcatT   = (bf16*)(ws + o_wcat);
    float* bcat    = (float*)(ws + o_bcat);
    bf16*  projT   = (bf16*)(ws + o_projT);
    bf16*  fc2T    = (bf16*)(ws + o_fc2T);

    k_wprep<<<NCAT / 64, 256, 0, stream>>>(wqkv_w, fc1_w, g1, g2, WcatT);
    k_bprep<<<(NCAT + 255) / 256, 256, 0, stream>>>(wqkv_w, fc1_w, wqkv_b, fc1_b, b1, b2v, bcat);
    k_wtrans<<<dim3(C / 64, C / 64), 256, 0, stream>>>(proj_w, projT, C, C);
    k_wtrans<<<dim3(C / 64, (HIDT + 63) / 64), 256, 0, stream>>>(fc2_w, fc2T, HIDT, C);

    k_precompute<<<M, 64, 0, stream>>>(td, wk_w, wk_b, wv_w, wv_b, fc_td_w, fc_td_b, kn, vvT, tdf);
    k_ln<<<B * N / 64, 256, 0, stream>>>(x, xn, xn32, acc);
    k_atdca<<<B * N / 4, 256, 0, stream>>>(xn32, g1, b1, wq_w, wq_b, ca_scale, kn, p_buf, tk_id);
    k_pv<<<dim3(B * N / 64, C / 64), 256, 0, stream>>>(p_buf, vvT, acc);
    k_gemm_fused<<<dim3(B * N / 128, NCAT / 96), 256, 0, stream>>>(xn, WcatT, bcat, qkv, hcat);
    k_sort_count<<<dim3(128, B), 128, 0, stream>>>(tk_id, ccnt);
    k_sort_scan<<<B, 128, 0, stream>>>(ccnt);
    k_sort_scatter<<<dim3(128, B), 128, 0, stream>>>(tk_id, ccnt, sidx);
    k_attn_mfma<<<dim3(NG, HEADS, B), 256, 0, stream>>>(qkv, sidx, o_bufp);
    k_gemm_big<C, 0><<<dim3(B * N / 128, C / 96), 256, 0, stream>>>(
        o_bufp, projT, proj_b, aca, nullptr);
    k_tdfill<<<(B * N * TDF + 255) / 256, 256, 0, stream>>>(tk_id, tdf, hcat);
    k_conv<<<dim3(64, 49, B), 256, 0, stream>>>(hcat, dw_w, dw_b, convsum);
    k_fc2ln<<<B * N / 32, 256, 0, stream>>>(convsum, fc2T, fc2_b, g3, b3, acc, aca, out);
}